// Round 2
// baseline (334.354 us; speedup 1.0000x reference)
//
#include <hip/hip_runtime.h>
#include <stdint.h>

// ---------------------------------------------------------------------------
// Fused causal MHA: qkv = x @ w_qkv^T ; flash-attn ; out = y @ w_out^T + b
// B=2, T=2048, C=1024, H=16, Dh=64.  bf16 MFMA compute, fp32 accumulate.
// Workspace budget: 40 MiB (Yb aliases xb; x is dead after GEMM1).
// ---------------------------------------------------------------------------

typedef __bf16 bf16x8 __attribute__((ext_vector_type(8)));
typedef float  f32x4  __attribute__((ext_vector_type(4)));

#define MFMA_16x16x32(a, b, c) __builtin_amdgcn_mfma_f32_16x16x32_bf16((a), (b), (c), 0, 0, 0)

__device__ __forceinline__ unsigned short f2bf(float f) {
    union { float f; unsigned int u; } c;
    c.f = f;
    unsigned int u = c.u;
    return (unsigned short)((u + 0x7fffu + ((u >> 16) & 1u)) >> 16);  // RNE
}

// ---------------- fp32 -> bf16 conversion (vectorized) ----------------
__global__ __launch_bounds__(256) void cvt_kernel(const float* __restrict__ in,
                                                  unsigned short* __restrict__ out,
                                                  int n4) {
    int i = blockIdx.x * 256 + threadIdx.x;
    const int stride = gridDim.x * 256;
    for (; i < n4; i += stride) {
        float4 v = reinterpret_cast<const float4*>(in)[i];
        ushort4 o;
        o.x = f2bf(v.x); o.y = f2bf(v.y); o.z = f2bf(v.z); o.w = f2bf(v.w);
        reinterpret_cast<ushort4*>(out)[i] = o;
    }
}

// ---------------- async global -> LDS, 16B per lane ----------------
__device__ __forceinline__ void gload_lds16(const void* g, void* l) {
    __builtin_amdgcn_global_load_lds((const __attribute__((address_space(1))) void*)g,
                                     (__attribute__((address_space(3))) void*)l,
                                     16, 0, 0);
}

// ---------------- shared GEMM core: C(128x128) = A(MxK) * B(NxK)^T ----------
// 256 threads = 4 waves in 2x2; each wave owns a 64x64 sub-tile (4x4 frags).
// BK = 32 (one 16x16x32 MFMA K-step). Single LDS buffer, 2 barriers / K-step.
__device__ __forceinline__ void gemm_core_128(const unsigned short* __restrict__ A,
                                              const unsigned short* __restrict__ B,
                                              int K, int tM, int tN,
                                              unsigned short* As, unsigned short* Bs,
                                              f32x4 acc[4][4]) {
    const int tid  = threadIdx.x;
    const int lane = tid & 63;
    const int w    = tid >> 6;
    const int wr   = w >> 1, wc = w & 1;
    const int lr   = lane & 15, lg = lane >> 4;

    // staging byte offsets (linear in tid -> matches global_load_lds lane order)
    const int o0 = tid * 16;        // issue 0: bytes [0, 4096)
    const int o1 = o0 + 4096;       // issue 1: bytes [4096, 8192)
    const int row0 = o0 >> 6, cb0 = o0 & 63;   // 64 B per 32-elem bf16 row
    const int row1 = o1 >> 6, cb1 = o1 & 63;

    const char* Ab = (const char*)A;
    const char* Bb = (const char*)B;
    const size_t rstride = (size_t)K * 2;  // bytes per row

    for (int kt = 0; kt < K; kt += 32) {
        const size_t kbyte = (size_t)kt * 2;
        gload_lds16(Ab + (size_t)(tM + row0) * rstride + kbyte + cb0, (char*)As + o0);
        gload_lds16(Ab + (size_t)(tM + row1) * rstride + kbyte + cb1, (char*)As + o1);
        gload_lds16(Bb + (size_t)(tN + row0) * rstride + kbyte + cb0, (char*)Bs + o0);
        gload_lds16(Bb + (size_t)(tN + row1) * rstride + kbyte + cb1, (char*)Bs + o1);
        __syncthreads();   // drains vmcnt -> staged data visible

        bf16x8 a[4], b[4];
#pragma unroll
        for (int m = 0; m < 4; ++m)
            a[m] = *reinterpret_cast<const bf16x8*>(As + (wr * 64 + m * 16 + lr) * 32 + lg * 8);
#pragma unroll
        for (int n = 0; n < 4; ++n)
            b[n] = *reinterpret_cast<const bf16x8*>(Bs + (wc * 64 + n * 16 + lr) * 32 + lg * 8);
#pragma unroll
        for (int m = 0; m < 4; ++m)
#pragma unroll
            for (int n = 0; n < 4; ++n)
                acc[m][n] = MFMA_16x16x32(a[m], b[n], acc[m][n]);
        __syncthreads();   // all waves done reading before next stage
    }
}

// ---------------- GEMM1: qkv projection, scatter epilogue ----------------
// A = x_bf16 (4096 x 1024), B = w_qkv_bf16 (3072 x 1024).
// C element (gr, gc): gr = b*2048 + t ; gc in [0,3072): kind|head|d.
// Writes Q (b,h,t,d) pre-scaled by 0.125, K (b,h,t,d), V transposed (b,h,d,t).
__global__ __launch_bounds__(256) void gemm_qkv_kernel(const unsigned short* __restrict__ Xb,
                                                       const unsigned short* __restrict__ Wb,
                                                       unsigned short* __restrict__ Qo,
                                                       unsigned short* __restrict__ Ko,
                                                       unsigned short* __restrict__ Vt) {
    __shared__ __align__(16) unsigned short As[128 * 32];
    __shared__ __align__(16) unsigned short Bs[128 * 32];
    f32x4 acc[4][4];
#pragma unroll
    for (int m = 0; m < 4; ++m)
#pragma unroll
        for (int n = 0; n < 4; ++n)
#pragma unroll
            for (int r = 0; r < 4; ++r) acc[m][n][r] = 0.0f;

    const int tM = blockIdx.y * 128, tN = blockIdx.x * 128;
    gemm_core_128(Xb, Wb, 1024, tM, tN, As, Bs, acc);

    const int lane = threadIdx.x & 63, w = threadIdx.x >> 6;
    const int wr = w >> 1, wc = w & 1, lr = lane & 15, lg = lane >> 4;
#pragma unroll
    for (int m = 0; m < 4; ++m)
#pragma unroll
        for (int n = 0; n < 4; ++n)
#pragma unroll
            for (int r = 0; r < 4; ++r) {
                const int gr = tM + wr * 64 + m * 16 + 4 * lg + r;  // b*2048 + t
                const int gc = tN + wc * 64 + n * 16 + lr;          // f in [0,3072)
                const float v = acc[m][n][r];
                const int bb = gr >> 11, t = gr & 2047;
                const int kind = gc >> 10, c = gc & 1023;
                const int h = c >> 6, d = c & 63;
                const int bh = bb * 16 + h;
                if (kind == 0)      Qo[((size_t)bh * 2048 + t) * 64 + d] = f2bf(v * 0.125f);
                else if (kind == 1) Ko[((size_t)bh * 2048 + t) * 64 + d] = f2bf(v);
                else                Vt[((size_t)bh * 64 + d) * 2048 + t] = f2bf(v);
            }
}

// ---------------- GEMM2: output projection + bias ----------------
__global__ __launch_bounds__(256) void gemm_out_kernel(const unsigned short* __restrict__ Yb,
                                                       const unsigned short* __restrict__ Wob,
                                                       const float* __restrict__ bias,
                                                       float* __restrict__ out) {
    __shared__ __align__(16) unsigned short As[128 * 32];
    __shared__ __align__(16) unsigned short Bs[128 * 32];
    f32x4 acc[4][4];
#pragma unroll
    for (int m = 0; m < 4; ++m)
#pragma unroll
        for (int n = 0; n < 4; ++n)
#pragma unroll
            for (int r = 0; r < 4; ++r) acc[m][n][r] = 0.0f;

    const int tM = blockIdx.y * 128, tN = blockIdx.x * 128;
    gemm_core_128(Yb, Wob, 1024, tM, tN, As, Bs, acc);

    const int lane = threadIdx.x & 63, w = threadIdx.x >> 6;
    const int wr = w >> 1, wc = w & 1, lr = lane & 15, lg = lane >> 4;
#pragma unroll
    for (int m = 0; m < 4; ++m)
#pragma unroll
        for (int n = 0; n < 4; ++n)
#pragma unroll
            for (int r = 0; r < 4; ++r) {
                const int gr = tM + wr * 64 + m * 16 + 4 * lg + r;
                const int gc = tN + wc * 64 + n * 16 + lr;
                out[(size_t)gr * 1024 + gc] = acc[m][n][r] + bias[gc];
            }
}

// ---------------- flash attention (causal, online softmax) ----------------
// Grid: 512 blocks = (b,h) x 16 q-blocks of 128. 4 waves/block; each wave
// owns 32 q-rows. KV tile = 32. Q,K layout (b,h,t,d); V transposed (b,h,d,t).
// Q pre-scaled by 1/sqrt(Dh). Per-wave P round-trip through LDS (bf16).
__global__ __launch_bounds__(256) void attn_kernel(const unsigned short* __restrict__ Q,
                                                   const unsigned short* __restrict__ Kb,
                                                   const unsigned short* __restrict__ Vt,
                                                   unsigned short* __restrict__ Y) {
    __shared__ __align__(16) unsigned short P_lds[4][32][32];
    const int tid = threadIdx.x, lane = tid & 63, w = tid >> 6;
    const int lr = lane & 15, lg = lane >> 4;
    const int bid  = blockIdx.x;
    const int qblk = 15 - (bid & 15);   // descending cost order for balance
    const int bh   = bid >> 4;          // b*16 + h
    const unsigned short* Qh = Q  + (size_t)bh * 2048 * 64;
    const unsigned short* Kh = Kb + (size_t)bh * 2048 * 64;
    const unsigned short* Vh = Vt + (size_t)bh * 64 * 2048;
    const int qw = qblk * 128 + w * 32;  // first q row of this wave

    // Q fragments: rows qw..qw+31, hoisted (A-frag: row = lane%16, k = 8*(lane/16)+j)
    bf16x8 aq[2][2];
#pragma unroll
    for (int m = 0; m < 2; ++m)
#pragma unroll
        for (int kk = 0; kk < 2; ++kk)
            aq[m][kk] = *reinterpret_cast<const bf16x8*>(Qh + (size_t)(qw + m * 16 + lr) * 64 + kk * 32 + lg * 8);

    f32x4 o[2][4];
    float mrun[2][4], lrun[2][4];
#pragma unroll
    for (int m = 0; m < 2; ++m) {
#pragma unroll
        for (int nd = 0; nd < 4; ++nd)
#pragma unroll
            for (int r = 0; r < 4; ++r) o[m][nd][r] = 0.0f;
#pragma unroll
        for (int r = 0; r < 4; ++r) { mrun[m][r] = -INFINITY; lrun[m][r] = 0.0f; }
    }

    for (int kb = 0; kb <= qw; kb += 32) {
        // ---- S = Q K^T (rows q, cols kv) ----
        f32x4 s[2][2];
#pragma unroll
        for (int m = 0; m < 2; ++m)
#pragma unroll
            for (int n = 0; n < 2; ++n)
#pragma unroll
                for (int r = 0; r < 4; ++r) s[m][n][r] = 0.0f;

        bf16x8 bk[2][2];
#pragma unroll
        for (int n = 0; n < 2; ++n)
#pragma unroll
            for (int kk = 0; kk < 2; ++kk)
                bk[n][kk] = *reinterpret_cast<const bf16x8*>(Kh + (size_t)(kb + n * 16 + lr) * 64 + kk * 32 + lg * 8);
#pragma unroll
        for (int m = 0; m < 2; ++m)
#pragma unroll
            for (int n = 0; n < 2; ++n)
#pragma unroll
                for (int kk = 0; kk < 2; ++kk)
                    s[m][n] = MFMA_16x16x32(aq[m][kk], bk[n][kk], s[m][n]);

        // ---- causal mask (only the diagonal tile) ----
        if (kb == qw) {
#pragma unroll
            for (int m = 0; m < 2; ++m)
#pragma unroll
                for (int n = 0; n < 2; ++n)
#pragma unroll
                    for (int r = 0; r < 4; ++r)
                        if (n * 16 + lr > m * 16 + 4 * lg + r) s[m][n][r] = -INFINITY;
        }

        // ---- online softmax: row stats across 16-lane groups ----
        float al[2][4], rs[2][4];
#pragma unroll
        for (int m = 0; m < 2; ++m)
#pragma unroll
            for (int r = 0; r < 4; ++r) {
                float v = fmaxf(s[m][0][r], s[m][1][r]);
                v = fmaxf(v, __shfl_xor(v, 1, 64));
                v = fmaxf(v, __shfl_xor(v, 2, 64));
                v = fmaxf(v, __shfl_xor(v, 4, 64));
                v = fmaxf(v, __shfl_xor(v, 8, 64));
                const float mn = fmaxf(mrun[m][r], v);
                al[m][r] = __expf(mrun[m][r] - mn);
                mrun[m][r] = mn;
                rs[m][r] = 0.0f;
            }
#pragma unroll
        for (int m = 0; m < 2; ++m)
#pragma unroll
            for (int n = 0; n < 2; ++n)
#pragma unroll
                for (int r = 0; r < 4; ++r) {
                    const float p = __expf(s[m][n][r] - mrun[m][r]);  // -inf -> 0
                    s[m][n][r] = p;
                    rs[m][r] += p;
                }
#pragma unroll
        for (int m = 0; m < 2; ++m)
#pragma unroll
            for (int r = 0; r < 4; ++r) {
                float v = rs[m][r];
                v += __shfl_xor(v, 1, 64);
                v += __shfl_xor(v, 2, 64);
                v += __shfl_xor(v, 4, 64);
                v += __shfl_xor(v, 8, 64);
                lrun[m][r] = lrun[m][r] * al[m][r] + v;
            }

        // ---- rescale O, stage P to LDS (bf16) ----
#pragma unroll
        for (int m = 0; m < 2; ++m)
#pragma unroll
            for (int nd = 0; nd < 4; ++nd)
#pragma unroll
                for (int r = 0; r < 4; ++r) o[m][nd][r] *= al[m][r];
#pragma unroll
        for (int m = 0; m < 2; ++m)
#pragma unroll
            for (int n = 0; n < 2; ++n)
#pragma unroll
                for (int r = 0; r < 4; ++r)
                    P_lds[w][m * 16 + 4 * lg + r][n * 16 + lr] = f2bf(s[m][n][r]);

        // ---- O += P V  (A = P from LDS, B = V^T-contiguous fragments) ----
        bf16x8 bv[4], ap[2];
#pragma unroll
        for (int nd = 0; nd < 4; ++nd)
            bv[nd] = *reinterpret_cast<const bf16x8*>(Vh + (size_t)(nd * 16 + lr) * 2048 + kb + lg * 8);
#pragma unroll
        for (int m = 0; m < 2; ++m)
            ap[m] = *reinterpret_cast<const bf16x8*>(&P_lds[w][m * 16 + lr][lg * 8]);
#pragma unroll
        for (int m = 0; m < 2; ++m)
#pragma unroll
            for (int nd = 0; nd < 4; ++nd)
                o[m][nd] = MFMA_16x16x32(ap[m], bv[nd], o[m][nd]);
    }

    // ---- epilogue: y = O / l, write (b, t, h*64+d) bf16 ----
    const int b = bh >> 4, h = bh & 15;
#pragma unroll
    for (int m = 0; m < 2; ++m)
#pragma unroll
        for (int r = 0; r < 4; ++r) {
            const float inv = 1.0f / lrun[m][r];
            const int t = qw + m * 16 + 4 * lg + r;
#pragma unroll
            for (int nd = 0; nd < 4; ++nd) {
                const int d = nd * 16 + lr;
                Y[((size_t)(b * 2048 + t)) * 1024 + h * 64 + d] = f2bf(o[m][nd][r] * inv);
            }
        }
}

// ---------------------------------------------------------------------------
extern "C" void kernel_launch(void* const* d_in, const int* in_sizes, int n_in,
                              void* d_out, int out_size, void* d_ws, size_t ws_size,
                              hipStream_t stream) {
    (void)in_sizes; (void)n_in; (void)out_size; (void)ws_size;
    const float* x     = (const float*)d_in[0];
    const float* w_qkv = (const float*)d_in[1];
    const float* w_out = (const float*)d_in[2];
    const float* b_out = (const float*)d_in[3];
    float* out = (float*)d_out;

    // Workspace layout (bf16 elements). Total = 20.5M elems = 41 MiB.
    // Yb ALIASES xb: x is consumed by gemm_qkv (kernel 3); attn (kernel 5)
    // writes Yb strictly after on the same stream.
    unsigned short* xb    = (unsigned short*)d_ws;                    // 4096x1024 (8 MiB)
    unsigned short* Yb    = xb;                                       // alias (post-GEMM1)
    unsigned short* wqkvb = xb    + (size_t)4096 * 1024;              // 3072x1024 (6 MiB)
    unsigned short* woutb = wqkvb + (size_t)3072 * 1024;              // 1024x1024 (2 MiB)
    unsigned short* Qb    = woutb + (size_t)1024 * 1024;              // 32x2048x64 (8 MiB)
    unsigned short* Kbuf  = Qb    + (size_t)32 * 2048 * 64;           // 32x2048x64 (8 MiB)
    unsigned short* Vt    = Kbuf  + (size_t)32 * 2048 * 64;           // 32x64x2048 (8 MiB)

    cvt_kernel<<<1024, 256, 0, stream>>>(x,     xb,    4096 * 1024 / 4);
    cvt_kernel<<<1024, 256, 0, stream>>>(w_qkv, wqkvb, 3072 * 1024 / 4);
    cvt_kernel<<<512,  256, 0, stream>>>(w_out, woutb, 1024 * 1024 / 4);
    gemm_qkv_kernel<<<dim3(24, 32), 256, 0, stream>>>(xb, wqkvb, Qb, Kbuf, Vt);
    attn_kernel<<<512, 256, 0, stream>>>(Qb, Kbuf, Vt, Yb);
    gemm_out_kernel<<<dim3(8, 32), 256, 0, stream>>>(Yb, woutb, b_out, out);
}